// Round 14
// baseline (199.941 us; speedup 1.0000x reference)
//
#include <hip/hip_runtime.h>
#include <hip/hip_bf16.h>

typedef __bf16 bf16;
typedef __attribute__((ext_vector_type(4))) float f32x4;
typedef __attribute__((ext_vector_type(8))) __bf16 bf16x8;
typedef __attribute__((ext_vector_type(4))) __bf16 bf16x4;

// async global->LDS, 16B per lane; LDS dest must be wave-uniform base + lane*16
static __device__ __forceinline__ void gl16(const void* g, void* l) {
  __builtin_amdgcn_global_load_lds((const __attribute__((address_space(1))) void*)g,
                                   (__attribute__((address_space(3))) void*)l, 16, 0, 0);
}
// fragment read from a [*][64] bf16 tile, 16B-unit XOR swizzle by (row&7)
static __device__ __forceinline__ bf16x8 frag(const bf16* tile, int row, int kb) {
  return *(const bf16x8*)(tile + row * 64 + ((((kb) >> 3) ^ (row & 7)) << 3));
}

// ---------------------------------------------------------------------------
// Weight prepass: 4x [256][256] f32 -> bf16 row-major.
// ---------------------------------------------------------------------------
__global__ void wpre(const float* __restrict__ w0, const float* __restrict__ w1,
                     const float* __restrict__ w2, const float* __restrict__ w3,
                     bf16* __restrict__ dst) {
  const float* srcs[4] = {w0, w1, w2, w3};
  const float* s = srcs[blockIdx.y];
  bf16* d = dst + (size_t)blockIdx.y * 65536;
  int base = blockIdx.x * 2048 + threadIdx.x * 8;
  f32x4 a = *(const f32x4*)(s + base);
  f32x4 b = *(const f32x4*)(s + base + 4);
  bf16x8 v = {(bf16)a[0], (bf16)a[1], (bf16)a[2], (bf16)a[3],
              (bf16)b[0], (bf16)b[1], (bf16)b[2], (bf16)b[3]};
  *(bf16x8*)(d + base) = v;
}

// ===========================================================================
// NEW: streaming transpose. src f32 CHANNEL-major [B][256][P] -> dst bf16
// PIXEL-major [B][P][256]. Tile = 400 px x 32 k. Reads are 1.6KB contiguous
// per k-row (the whole point: replace the 256B/25.6KB-stride pattern that
// capped every GEMM at ~1TB/s). Writes 64B-aligned 64B segments.
// ===========================================================================
__global__ __launch_bounds__(256, 4)
void tpose(const float* __restrict__ src, bf16* __restrict__ dst, int P) {
  __shared__ bf16 tile[400][40];  // [px][32k + 8 pad] = 32KB
  const int t = threadIdx.x;
  const int p0 = blockIdx.x * 400;
  const int k0 = blockIdx.y * 32;
  const int b = blockIdx.z;
  const float* s = src + (size_t)b * 256 * P + (size_t)k0 * P + p0;
  bf16* d = dst + (size_t)b * P * 256 + (size_t)p0 * 256 + k0;

  // read: 32 rows x 100 f32x4 (1.6KB contiguous per row) = 3200 units
#pragma unroll
  for (int pass = 0; pass < 13; ++pass) {
    int idx = pass * 256 + t;
    if (idx < 3200) {
      int r = idx / 100, sg = idx - r * 100;
      f32x4 v = *(const f32x4*)(s + (size_t)r * P + sg * 4);
#pragma unroll
      for (int j = 0; j < 4; ++j) tile[sg * 4 + j][r] = (bf16)v[j];
    }
  }
  __syncthreads();
  // write: 400 px-rows x 4 bf16x8 (64B per row, 64B-aligned) = 1600 units
#pragma unroll
  for (int pass = 0; pass < 7; ++pass) {
    int idx = pass * 256 + t;
    if (idx < 1600) {
      int row = idx >> 2, u = idx & 3;
      bf16x8 v = *(const bf16x8*)&tile[row][u * 8];
      *(bf16x8*)(d + (size_t)row * 256 + u * 8) = v;
    }
  }
}

// ===========================================================================
// Fused Q-projection + score. act now PIXEL-major bf16 (from tpose):
// staged via gl16 (contiguous 128B row-chunks, L3-resident). W L2-direct.
// Block: 64 px x 256 out-ch, 256 threads. Score epilogue unchanged.
// ===========================================================================
__global__ __launch_bounds__(256, 3)
void qscore(const bf16* __restrict__ Qraw, const bf16* __restrict__ Wq,
            const float* __restrict__ bq, const bf16* __restrict__ Kpm,
            float* __restrict__ score) {
  __shared__ alignas(16) char smem[64 * 264 * 2];  // act dbuf (16KB) / Qs
  const int t = threadIdx.x;
  const int b = blockIdx.z;
  const int p0 = blockIdx.x * 64;
  const int w = t >> 6, l = t & 63;
  const int lrow = l & 15, ksel = l >> 4;
  const bf16* actb = Qraw + (size_t)b * 6400 * 256;

  auto Ab = [&](int buf) { return (bf16*)(smem + buf * 8192); };

  auto GLOADA = [&](int kt, int buf) {
    const int k0 = kt * 64;
#pragma unroll
    for (int call = 0; call < 2; ++call) {
      int idx = call * 256 + t;
      int row = idx >> 3, u = idx & 7;
      gl16(actb + (size_t)(p0 + row) * 256 + k0 + ((u ^ (row & 7)) << 3), Ab(buf) + idx * 8);
    }
  };

  f32x4 acc[4][4];
#pragma unroll
  for (int i = 0; i < 4; ++i)
#pragma unroll
    for (int j = 0; j < 4; ++j) acc[i][j] = (f32x4){0.f, 0.f, 0.f, 0.f};

  auto COMPUTE = [&](int kt, int buf) {
    const int k0 = kt * 64;
    bf16x8 af[4][2];
#pragma unroll
    for (int mi = 0; mi < 4; ++mi)
#pragma unroll
      for (int kk = 0; kk < 2; ++kk)
        af[mi][kk] = *(const bf16x8*)(Wq + (size_t)(w * 64 + mi * 16 + lrow) * 256 +
                                      k0 + kk * 32 + ksel * 8);
    bf16x8 bv[4][2];
#pragma unroll
    for (int ni = 0; ni < 4; ++ni)
#pragma unroll
      for (int kk = 0; kk < 2; ++kk)
        bv[ni][kk] = frag(Ab(buf), ni * 16 + lrow, kk * 32 + ksel * 8);
#pragma unroll
    for (int kk = 0; kk < 2; ++kk)
#pragma unroll
      for (int mi = 0; mi < 4; ++mi)
#pragma unroll
        for (int ni = 0; ni < 4; ++ni)
          acc[mi][ni] = __builtin_amdgcn_mfma_f32_16x16x32_bf16(af[mi][kk], bv[ni][kk],
                                                                acc[mi][ni], 0, 0, 0);
  };

  GLOADA(0, 0);
  __syncthreads();
#pragma unroll
  for (int kt = 0; kt < 4; ++kt) {
    if (kt < 3) GLOADA(kt + 1, (kt + 1) & 1);
    __builtin_amdgcn_sched_barrier(0);
    COMPUTE(kt, kt & 1);
    __syncthreads();
  }

  // ---- dump Q (with bias) to LDS Qs[64 px][264 ch-stride] ----
  bf16* Qs = (bf16*)smem;
#pragma unroll
  for (int mi = 0; mi < 4; ++mi) {
#pragma unroll
    for (int r = 0; r < 4; ++r) {
      int o = w * 64 + mi * 16 + ksel * 4 + r;
      float bvf = bq[o];
#pragma unroll
      for (int ni = 0; ni < 4; ++ni) {
        int px = ni * 16 + lrow;
        Qs[px * 264 + o] = (bf16)(acc[mi][ni][r] + bvf);
      }
    }
  }
  __syncthreads();

  {
    int pl = t & 63, hd = t >> 6;
    int p = p0 + pl;
    int x = p / 80, y = p % 80;
    float cx = 0.5f * x - 0.25f;
    int ix = (int)floorf(cx);
    float wx1 = cx - ix;
    int x0 = ix < 0 ? 0 : ix, x1 = (ix + 1 > 39) ? 39 : ix + 1;
    float cy = 0.5f * y - 0.25f;
    int iy = (int)floorf(cy);
    float wy1 = cy - iy;
    int y0 = iy < 0 ? 0 : iy, y1 = (iy + 1 > 39) ? 39 : iy + 1;
    float w00 = (1.f - wx1) * (1.f - wy1), w01 = (1.f - wx1) * wy1;
    float w10 = wx1 * (1.f - wy1), w11 = wx1 * wy1;
    const bf16* k00 = Kpm + ((size_t)b * 1600 + x0 * 40 + y0) * 256 + hd * 64;
    const bf16* k01 = Kpm + ((size_t)b * 1600 + x0 * 40 + y1) * 256 + hd * 64;
    const bf16* k10 = Kpm + ((size_t)b * 1600 + x1 * 40 + y0) * 256 + hd * 64;
    const bf16* k11 = Kpm + ((size_t)b * 1600 + x1 * 40 + y1) * 256 + hd * 64;
    float dot = 0.f;
#pragma unroll
    for (int i = 0; i < 8; ++i) {
      bf16x8 qv = *(const bf16x8*)(Qs + pl * 264 + hd * 64 + i * 8);
      bf16x8 a = *(const bf16x8*)(k00 + i * 8);
      bf16x8 c = *(const bf16x8*)(k01 + i * 8);
      bf16x8 d = *(const bf16x8*)(k10 + i * 8);
      bf16x8 e = *(const bf16x8*)(k11 + i * 8);
#pragma unroll
      for (int j = 0; j < 8; ++j) {
        float kup = w00 * (float)a[j] + w01 * (float)c[j] + w10 * (float)d[j] + w11 * (float)e[j];
        dot += (float)qv[j] * kup;
      }
    }
    score[((size_t)b * 4 + hd) * 6400 + p] = dot * 0.0625f;
  }
}

// ---------------------------------------------------------------------------
// K+V projection: act now PIXEL-major bf16 (from tpose), staged via gl16
// with per-lane source clamp for the P=1600 tail. W via gl16 as before.
// ---------------------------------------------------------------------------
__global__ __launch_bounds__(512, 1)
void kv_gemm(const bf16* __restrict__ Kraw,
             const bf16* __restrict__ Wk, const float* __restrict__ bk, bf16* __restrict__ Kpm,
             const bf16* __restrict__ Wv, const float* __restrict__ bv, bf16* __restrict__ Vpm) {
  __shared__ alignas(16) char smem[65536];
  const int P = 1600;
  const int t = threadIdx.x;
  const int b = blockIdx.z;
  const int m0 = blockIdx.x * 128;
  const int sel = blockIdx.y >> 1;
  const int n0 = (blockIdx.y & 1) * 128;
  const bf16* W = sel ? Wv : Wk;
  const float* bias = sel ? bv : bk;
  bf16* out = sel ? Vpm : Kpm;
  const int w = t >> 6, l = t & 63;
  const int wr = w & 1, wc = w >> 1;
  const int lrow = l & 15, koff = (l >> 4) * 8;
  const bf16* actb = Kraw + (size_t)b * P * 256;

  f32x4 acc[4][2];
#pragma unroll
  for (int i = 0; i < 4; ++i)
#pragma unroll
    for (int j = 0; j < 2; ++j) acc[i][j] = (f32x4){0.f, 0.f, 0.f, 0.f};

  auto Ab = [&](int buf) { return (bf16*)(smem + buf * 16384); };
  auto Bb = [&](int buf) { return (bf16*)(smem + 32768 + buf * 16384); };

  auto GLOADB = [&](int kt, int buf) {
    const int k0 = kt * 64;
#pragma unroll
    for (int call = 0; call < 2; ++call) {
      int idx = call * 512 + t;
      int row = idx >> 3, u = idx & 7;
      gl16(W + (size_t)(n0 + row) * 256 + k0 + ((u ^ (row & 7)) << 3), Bb(buf) + idx * 8);
    }
  };
  auto GLOADA = [&](int kt, int buf) {
    const int k0 = kt * 64;
#pragma unroll
    for (int call = 0; call < 2; ++call) {
      int idx = call * 512 + t;
      int row = idx >> 3, u = idx & 7;
      int pr = m0 + row; if (pr > P - 1) pr = P - 1;  // tail: dup rows, masked at write
      gl16(actb + (size_t)pr * 256 + k0 + ((u ^ (row & 7)) << 3), Ab(buf) + idx * 8);
    }
  };
  auto COMPUTE = [&](int buf) {
#pragma unroll
    for (int kk = 0; kk < 2; ++kk) {
      bf16x8 af[4], bvv[2];
      const int kb = kk * 32 + koff;
#pragma unroll
      for (int i = 0; i < 4; ++i) af[i] = frag(Ab(buf), wr * 64 + i * 16 + lrow, kb);
#pragma unroll
      for (int j = 0; j < 2; ++j) bvv[j] = frag(Bb(buf), wc * 32 + j * 16 + lrow, kb);
#pragma unroll
      for (int i = 0; i < 4; ++i)
#pragma unroll
        for (int j = 0; j < 2; ++j)
          acc[i][j] = __builtin_amdgcn_mfma_f32_16x16x32_bf16(af[i], bvv[j], acc[i][j], 0, 0, 0);
    }
  };

  GLOADB(0, 0);
  GLOADA(0, 0);
  __syncthreads();
#pragma unroll
  for (int kt = 0; kt < 4; ++kt) {
    const int cur = kt & 1;
    if (kt < 3) { GLOADB(kt + 1, cur ^ 1); GLOADA(kt + 1, cur ^ 1); }
    __builtin_amdgcn_sched_barrier(0);
    COMPUTE(cur);
    __syncthreads();
  }

  bf16* Sc = (bf16*)smem;
#pragma unroll
  for (int mi = 0; mi < 4; ++mi) {
#pragma unroll
    for (int ni = 0; ni < 2; ++ni) {
      int ch = wc * 32 + ni * 16 + (l & 15);
      float bvf = bias[n0 + ch];
#pragma unroll
      for (int r = 0; r < 4; ++r) {
        int p = wr * 64 + mi * 16 + (l >> 4) * 4 + r;
        Sc[p * 136 + ch] = (bf16)(acc[mi][ni][r] + bvf);
      }
    }
  }
  __syncthreads();
  bf16* ob = out + (size_t)b * P * 256;
#pragma unroll
  for (int pass = 0; pass < 4; ++pass) {
    int unit = pass * 512 + t;
    int row = unit >> 4, cu = unit & 15;
    if (m0 + row < P) {
      bf16x8 v = *(const bf16x8*)(Sc + row * 136 + cu * 8);
      *(bf16x8*)(ob + (size_t)(m0 + row) * 256 + n0 + cu * 8) = v;
    }
  }
}

// ---------------------------------------------------------------------------
// In-place column softmax over x (per b,hd,y), x4 (R2 sum) folded in.
// ---------------------------------------------------------------------------
__global__ void smax_kernel(float* __restrict__ score) {
  __shared__ float s[6400];
  const int hd = blockIdx.x, b = blockIdx.y, t = threadIdx.x;
  float* buf = score + ((size_t)b * 4 + hd) * 6400;
  for (int i = t; i < 6400; i += 256) s[i] = buf[i];
  __syncthreads();
  if (t < 80) {
    const int y = t;
    float m = -1e30f;
    for (int x = 0; x < 80; ++x) m = fmaxf(m, s[x * 80 + y]);
    float sum = 0.f;
    for (int x = 0; x < 80; ++x) {
      float e = __expf(s[x * 80 + y] - m);
      s[x * 80 + y] = e;
      sum += e;
    }
    float inv = 4.0f / sum;
    for (int x = 0; x < 80; ++x) buf[x * 80 + y] = s[x * 80 + y] * inv;
  }
}

// ===========================================================================
// Uv[b][hd][o][q] = sum_{c<64} wo[o][hd*64+c] * V[b][q][hd*64+c]  (unchanged)
// ===========================================================================
__global__ __launch_bounds__(256, 4)
void uv_gemm(const bf16* __restrict__ Vpm, const bf16* __restrict__ Wo,
             bf16* __restrict__ Uv) {
  __shared__ alignas(16) bf16 Vt[64 * 64];
  const int t = threadIdx.x;
  const int b = blockIdx.z;
  const int hd = blockIdx.y;
  const int q0 = blockIdx.x * 64;
  const int w = t >> 6, l = t & 63;
  const int lrow = l & 15, ksel = l >> 4;

  const bf16* vsrc = Vpm + ((size_t)b * 1600 + q0) * 256 + hd * 64;
#pragma unroll
  for (int call = 0; call < 2; ++call) {
    int idx = (w * 2 + call) * 64 + l;
    int q = idx >> 3, u = idx & 7;
    gl16(vsrc + (size_t)q * 256 + ((u ^ (q & 7)) << 3), Vt + idx * 8);
  }
  asm volatile("s_waitcnt vmcnt(0)" ::: "memory");
  __syncthreads();

  f32x4 acc[4][4];
#pragma unroll
  for (int i = 0; i < 4; ++i)
#pragma unroll
    for (int j = 0; j < 4; ++j) acc[i][j] = (f32x4){0.f, 0.f, 0.f, 0.f};

#pragma unroll
  for (int kk = 0; kk < 2; ++kk) {
    bf16x8 af[4], bv[4];
#pragma unroll
    for (int mi = 0; mi < 4; ++mi)
      af[mi] = *(const bf16x8*)(Wo + (size_t)(w * 64 + mi * 16 + lrow) * 256 +
                                hd * 64 + kk * 32 + ksel * 8);
#pragma unroll
    for (int ni = 0; ni < 4; ++ni)
      bv[ni] = frag(Vt, ni * 16 + lrow, kk * 32 + ksel * 8);
#pragma unroll
    for (int mi = 0; mi < 4; ++mi)
#pragma unroll
      for (int ni = 0; ni < 4; ++ni)
        acc[mi][ni] = __builtin_amdgcn_mfma_f32_16x16x32_bf16(af[mi], bv[ni], acc[mi][ni], 0, 0, 0);
  }

  bf16* ob = Uv + ((size_t)(b * 4 + hd)) * 256 * 1600;
#pragma unroll
  for (int mi = 0; mi < 4; ++mi) {
#pragma unroll
    for (int ni = 0; ni < 4; ++ni) {
#pragma unroll
      for (int r = 0; r < 4; ++r) {
        int o = w * 64 + mi * 16 + ksel * 4 + r;
        int q = q0 + ni * 16 + lrow;
        ob[(size_t)o * 1600 + q] = (bf16)acc[mi][ni][r];
      }
    }
  }
}

// ===========================================================================
// combine (unchanged from round 13): one block per (o, b), coalesced writes.
// ===========================================================================
__global__ __launch_bounds__(256, 8)
void combine(const bf16* __restrict__ Uv, const float* __restrict__ attn,
             const float* __restrict__ bo, float* __restrict__ out) {
  __shared__ bf16 Us[4][1600];
  __shared__ int   sx0[80], sx1[80];
  __shared__ float swx[80];
  const int t = threadIdx.x;
  const int o = blockIdx.x;
  const int b = blockIdx.y;

  const bf16* usrc = Uv + (size_t)(b * 4) * 256 * 1600 + (size_t)o * 1600;
  for (int idx = t; idx < 800; idx += 256) {
    int hd = idx / 200, u = idx % 200;
    *(bf16x8*)&Us[hd][u * 8] = *(const bf16x8*)(usrc + (size_t)hd * 256 * 1600 + u * 8);
  }
  if (t < 80) {
    float c = 0.5f * t - 0.25f;
    int i0 = (int)floorf(c);
    swx[t] = c - i0;
    sx0[t] = i0 < 0 ? 0 : i0;
    sx1[t] = (i0 + 1 > 39) ? 39 : i0 + 1;
  }
  __syncthreads();

  const float bias = bo[o];
  const float* attb = attn + (size_t)b * 4 * 6400;
  float* op = out + ((size_t)b * 256 + o) * 6400;

  for (int p = t; p < 6400; p += 256) {
    int x = p / 80, y = p - x * 80;
    int x0 = sx0[x], x1 = sx1[x], y0 = sx0[y], y1 = sx1[y];
    float wx1 = swx[x], wy1 = swx[y];
    float w00 = (1.f - wx1) * (1.f - wy1), w01 = (1.f - wx1) * wy1;
    float w10 = wx1 * (1.f - wy1), w11 = wx1 * wy1;
    int q00 = x0 * 40 + y0, q01 = x0 * 40 + y1, q10 = x1 * 40 + y0, q11 = x1 * 40 + y1;
    float acc = bias;
#pragma unroll
    for (int hd = 0; hd < 4; ++hd) {
      float up = w00 * (float)Us[hd][q00] + w01 * (float)Us[hd][q01] +
                 w10 * (float)Us[hd][q10] + w11 * (float)Us[hd][q11];
      acc += attb[hd * 6400 + p] * up;
    }
    op[p] = acc;
  }
}

// ---------------------------------------------------------------------------
extern "C" void kernel_launch(void* const* d_in, const int* in_sizes, int n_in,
                              void* d_out, int out_size, void* d_ws, size_t ws_size,
                              hipStream_t stream) {
  const float* query = (const float*)d_in[0];
  const float* key   = (const float*)d_in[1];
  const float* wq    = (const float*)d_in[2];
  const float* bq    = (const float*)d_in[3];
  const float* wk    = (const float*)d_in[4];
  const float* bk    = (const float*)d_in[5];
  const float* wv    = (const float*)d_in[6];
  const float* bv    = (const float*)d_in[7];
  const float* wo    = (const float*)d_in[8];
  const float* bo    = (const float*)d_in[9];

  // ws (85.7MB): [Qraw | later Uv] | Kpm | Vpm | score | Wb.  Kraw -> d_out.
  char* ws = (char*)d_ws;
  bf16*  Qraw  = (bf16*)(ws);              // 52,428,800 B; dead after qscore
  bf16*  Uv    = (bf16*)(ws);              // written by uv_gemm (after qscore)
  bf16*  Kpm   = (bf16*)(ws + 52428800);   // 13,107,200 B
  bf16*  Vpm   = (bf16*)(ws + 65536000);   // 13,107,200 B
  float* score = (float*)(ws + 78643200);  //  6,553,600 B
  bf16*  Wb    = (bf16*)(ws + 85196800);   //    524,288 B
  bf16* wqb = Wb, *wkb = Wb + 65536, *wvb = Wb + 131072, *wob = Wb + 196608;
  bf16*  Kraw  = (bf16*)d_out;             // 13.1MB in d_out; dead before combine

  wpre<<<dim3(32, 4), 256, 0, stream>>>(wq, wk, wv, wo, Wb);
  tpose<<<dim3(16, 8, 16), 256, 0, stream>>>(query, Qraw, 6400);
  tpose<<<dim3(4, 8, 16), 256, 0, stream>>>(key, Kraw, 1600);
  kv_gemm<<<dim3(13, 4, 16), 512, 0, stream>>>(Kraw, wkb, bk, Kpm, wvb, bv, Vpm);
  qscore<<<dim3(100, 1, 16), 256, 0, stream>>>(Qraw, wqb, bq, Kpm, score);
  smax_kernel<<<dim3(4, 16), 256, 0, stream>>>(score);
  uv_gemm<<<dim3(25, 4, 16), 256, 0, stream>>>(Vpm, wob, Uv);
  combine<<<dim3(256, 16), 256, 0, stream>>>(Uv, score, bo, (float*)d_out);
}

// Round 15
// 179.871 us; speedup vs baseline: 1.1116x; 1.1116x over previous
//
#include <hip/hip_runtime.h>
#include <hip/hip_bf16.h>

typedef __bf16 bf16;
typedef __attribute__((ext_vector_type(4))) float f32x4;
typedef __attribute__((ext_vector_type(8))) __bf16 bf16x8;
typedef __attribute__((ext_vector_type(4))) __bf16 bf16x4;

// async global->LDS, 16B per lane; LDS dest must be wave-uniform base + lane*16
static __device__ __forceinline__ void gl16(const void* g, void* l) {
  __builtin_amdgcn_global_load_lds((const __attribute__((address_space(1))) void*)g,
                                   (__attribute__((address_space(3))) void*)l, 16, 0, 0);
}
// fragment read from a [*][64] bf16 tile, 16B-unit XOR swizzle by (row&7)
static __device__ __forceinline__ bf16x8 frag(const bf16* tile, int row, int kb) {
  return *(const bf16x8*)(tile + row * 64 + ((((kb) >> 3) ^ (row & 7)) << 3));
}

// ---------------------------------------------------------------------------
// Weight prepass: 4x [256][256] f32 -> bf16 row-major.
// ---------------------------------------------------------------------------
__global__ void wpre(const float* __restrict__ w0, const float* __restrict__ w1,
                     const float* __restrict__ w2, const float* __restrict__ w3,
                     bf16* __restrict__ dst) {
  const float* srcs[4] = {w0, w1, w2, w3};
  const float* s = srcs[blockIdx.y];
  bf16* d = dst + (size_t)blockIdx.y * 65536;
  int base = blockIdx.x * 2048 + threadIdx.x * 8;
  f32x4 a = *(const f32x4*)(s + base);
  f32x4 b = *(const f32x4*)(s + base + 4);
  bf16x8 v = {(bf16)a[0], (bf16)a[1], (bf16)a[2], (bf16)a[3],
              (bf16)b[0], (bf16)b[1], (bf16)b[2], (bf16)b[3]};
  *(bf16x8*)(d + base) = v;
}

// ===========================================================================
// Fused Q-projection + score, SINGLE-STAGE: all 16 f32x4 staging loads issued
// back-to-back (16-deep MLP), one transpose pass to 4 swizzled LDS tiles,
// ONE barrier, then all 128 MFMAs barrier-free. W read L2-direct per kt.
// Block: 64 px x 256 out-ch, 256 threads (4 waves). Score epilogue unchanged.
// ===========================================================================
__global__ __launch_bounds__(256, 1)
void qscore(const float* __restrict__ query, const bf16* __restrict__ Wq,
            const float* __restrict__ bq, const bf16* __restrict__ Kpm,
            float* __restrict__ score) {
  __shared__ alignas(16) char smem[64 * 264 * 2];  // 33792B; act tiles use 32KB
  const int t = threadIdx.x;
  const int b = blockIdx.z;
  const int p0 = blockIdx.x * 64;
  const int w = t >> 6, l = t & 63;
  const int lrow = l & 15, ksel = l >> 4;
  const int pq = t & 15, cq = t >> 4;   // staging: px-quad (0..15), c-quad (0..15)
  const float* actb = query + (size_t)b * 256 * 6400;
  bf16* As = (bf16*)smem;               // 4 tiles of [64][64] bf16 (8KB each)

  // ---- stage: 16 loads, all K chunks at once ----
  f32x4 Ar[4][4];
#pragma unroll
  for (int kt = 0; kt < 4; ++kt)
#pragma unroll
    for (int j = 0; j < 4; ++j)
      Ar[kt][j] = *(const f32x4*)(actb + (size_t)(kt * 64 + cq * 4 + j) * 6400 + p0 + pq * 4);
#pragma unroll
  for (int kt = 0; kt < 4; ++kt) {
    bf16* tile = As + kt * 4096;
#pragma unroll
    for (int e = 0; e < 4; ++e) {       // 4x4 register mini-transpose
      int row = pq * 4 + e;
      bf16x4 v = {(bf16)Ar[kt][0][e], (bf16)Ar[kt][1][e], (bf16)Ar[kt][2][e], (bf16)Ar[kt][3][e]};
      *(bf16x4*)(tile + row * 64 + ((((cq >> 1) ^ (row & 7)) << 3) | ((cq & 1) << 2))) = v;
    }
  }
  __syncthreads();

  f32x4 acc[4][4];
#pragma unroll
  for (int i = 0; i < 4; ++i)
#pragma unroll
    for (int j = 0; j < 4; ++j) acc[i][j] = (f32x4){0.f, 0.f, 0.f, 0.f};

  // ---- compute: 4 K-chunks, no barriers between ----
#pragma unroll
  for (int kt = 0; kt < 4; ++kt) {
    const int k0 = kt * 64;
    const bf16* tile = As + kt * 4096;
    bf16x8 af[4][2], bv[4][2];
#pragma unroll
    for (int mi = 0; mi < 4; ++mi)
#pragma unroll
      for (int kk = 0; kk < 2; ++kk)
        af[mi][kk] = *(const bf16x8*)(Wq + (size_t)(w * 64 + mi * 16 + lrow) * 256 +
                                      k0 + kk * 32 + ksel * 8);
#pragma unroll
    for (int ni = 0; ni < 4; ++ni)
#pragma unroll
      for (int kk = 0; kk < 2; ++kk)
        bv[ni][kk] = frag(tile, ni * 16 + lrow, kk * 32 + ksel * 8);
#pragma unroll
    for (int kk = 0; kk < 2; ++kk)
#pragma unroll
      for (int mi = 0; mi < 4; ++mi)
#pragma unroll
        for (int ni = 0; ni < 4; ++ni)
          acc[mi][ni] = __builtin_amdgcn_mfma_f32_16x16x32_bf16(af[mi][kk], bv[ni][kk],
                                                                acc[mi][ni], 0, 0, 0);
  }
  __syncthreads();  // retire LDS reads before Qs overwrite

  // ---- dump Q (with bias) to LDS Qs[64 px][264 ch-stride] ----
  bf16* Qs = (bf16*)smem;
#pragma unroll
  for (int mi = 0; mi < 4; ++mi) {
#pragma unroll
    for (int r = 0; r < 4; ++r) {
      int o = w * 64 + mi * 16 + ksel * 4 + r;
      float bvf = bq[o];
#pragma unroll
      for (int ni = 0; ni < 4; ++ni) {
        int px = ni * 16 + lrow;
        Qs[px * 264 + o] = (bf16)(acc[mi][ni][r] + bvf);
      }
    }
  }
  __syncthreads();

  // ---- score: one thread per (pixel, head) ----
  {
    int pl = t & 63, hd = t >> 6;
    int p = p0 + pl;
    int x = p / 80, y = p % 80;
    float cx = 0.5f * x - 0.25f;
    int ix = (int)floorf(cx);
    float wx1 = cx - ix;
    int x0 = ix < 0 ? 0 : ix, x1 = (ix + 1 > 39) ? 39 : ix + 1;
    float cy = 0.5f * y - 0.25f;
    int iy = (int)floorf(cy);
    float wy1 = cy - iy;
    int y0 = iy < 0 ? 0 : iy, y1 = (iy + 1 > 39) ? 39 : iy + 1;
    float w00 = (1.f - wx1) * (1.f - wy1), w01 = (1.f - wx1) * wy1;
    float w10 = wx1 * (1.f - wy1), w11 = wx1 * wy1;
    const bf16* k00 = Kpm + ((size_t)b * 1600 + x0 * 40 + y0) * 256 + hd * 64;
    const bf16* k01 = Kpm + ((size_t)b * 1600 + x0 * 40 + y1) * 256 + hd * 64;
    const bf16* k10 = Kpm + ((size_t)b * 1600 + x1 * 40 + y0) * 256 + hd * 64;
    const bf16* k11 = Kpm + ((size_t)b * 1600 + x1 * 40 + y1) * 256 + hd * 64;
    float dot = 0.f;
#pragma unroll
    for (int i = 0; i < 8; ++i) {
      bf16x8 qv = *(const bf16x8*)(Qs + pl * 264 + hd * 64 + i * 8);
      bf16x8 a = *(const bf16x8*)(k00 + i * 8);
      bf16x8 c = *(const bf16x8*)(k01 + i * 8);
      bf16x8 d = *(const bf16x8*)(k10 + i * 8);
      bf16x8 e = *(const bf16x8*)(k11 + i * 8);
#pragma unroll
      for (int j = 0; j < 8; ++j) {
        float kup = w00 * (float)a[j] + w01 * (float)c[j] + w10 * (float)d[j] + w11 * (float)e[j];
        dot += (float)qv[j] * kup;
      }
    }
    score[((size_t)b * 4 + hd) * 6400 + p] = dot * 0.0625f;
  }
}

// ===========================================================================
// K+V projection, same single-stage structure. Block: 64 px x 256 o, 256t.
// blockIdx.y selects K vs V. Output pixel-major via LDS scratch (coalesced).
// 1600 = 25 x 64: no tail.
// ===========================================================================
__global__ __launch_bounds__(256, 1)
void kv_proj(const float* __restrict__ key,
             const bf16* __restrict__ Wk, const float* __restrict__ bk, bf16* __restrict__ Kpm,
             const bf16* __restrict__ Wv, const float* __restrict__ bv, bf16* __restrict__ Vpm) {
  __shared__ alignas(16) char smem[64 * 264 * 2];
  const int P = 1600;
  const int t = threadIdx.x;
  const int b = blockIdx.z;
  const int p0 = blockIdx.x * 64;
  const int sel = blockIdx.y;
  const bf16* W = sel ? Wv : Wk;
  const float* bias = sel ? bv : bk;
  bf16* out = sel ? Vpm : Kpm;
  const int w = t >> 6, l = t & 63;
  const int lrow = l & 15, ksel = l >> 4;
  const int pq = t & 15, cq = t >> 4;
  const float* actb = key + (size_t)b * 256 * P;
  bf16* As = (bf16*)smem;

  f32x4 Ar[4][4];
#pragma unroll
  for (int kt = 0; kt < 4; ++kt)
#pragma unroll
    for (int j = 0; j < 4; ++j)
      Ar[kt][j] = *(const f32x4*)(actb + (size_t)(kt * 64 + cq * 4 + j) * P + p0 + pq * 4);
#pragma unroll
  for (int kt = 0; kt < 4; ++kt) {
    bf16* tile = As + kt * 4096;
#pragma unroll
    for (int e = 0; e < 4; ++e) {
      int row = pq * 4 + e;
      bf16x4 v = {(bf16)Ar[kt][0][e], (bf16)Ar[kt][1][e], (bf16)Ar[kt][2][e], (bf16)Ar[kt][3][e]};
      *(bf16x4*)(tile + row * 64 + ((((cq >> 1) ^ (row & 7)) << 3) | ((cq & 1) << 2))) = v;
    }
  }
  __syncthreads();

  f32x4 acc[4][4];
#pragma unroll
  for (int i = 0; i < 4; ++i)
#pragma unroll
    for (int j = 0; j < 4; ++j) acc[i][j] = (f32x4){0.f, 0.f, 0.f, 0.f};

#pragma unroll
  for (int kt = 0; kt < 4; ++kt) {
    const int k0 = kt * 64;
    const bf16* tile = As + kt * 4096;
    bf16x8 af[4][2], bv8[4][2];
#pragma unroll
    for (int mi = 0; mi < 4; ++mi)
#pragma unroll
      for (int kk = 0; kk < 2; ++kk)
        af[mi][kk] = *(const bf16x8*)(W + (size_t)(w * 64 + mi * 16 + lrow) * 256 +
                                      k0 + kk * 32 + ksel * 8);
#pragma unroll
    for (int ni = 0; ni < 4; ++ni)
#pragma unroll
      for (int kk = 0; kk < 2; ++kk)
        bv8[ni][kk] = frag(tile, ni * 16 + lrow, kk * 32 + ksel * 8);
#pragma unroll
    for (int kk = 0; kk < 2; ++kk)
#pragma unroll
      for (int mi = 0; mi < 4; ++mi)
#pragma unroll
        for (int ni = 0; ni < 4; ++ni)
          acc[mi][ni] = __builtin_amdgcn_mfma_f32_16x16x32_bf16(af[mi][kk], bv8[ni][kk],
                                                                acc[mi][ni], 0, 0, 0);
  }
  __syncthreads();

  // ---- acc (with bias) -> LDS scratch [64 px][264], then coalesced write ----
  bf16* Sc = (bf16*)smem;
#pragma unroll
  for (int mi = 0; mi < 4; ++mi) {
#pragma unroll
    for (int r = 0; r < 4; ++r) {
      int o = w * 64 + mi * 16 + ksel * 4 + r;
      float bvf = bias[o];
#pragma unroll
      for (int ni = 0; ni < 4; ++ni) {
        int px = ni * 16 + lrow;
        Sc[px * 264 + o] = (bf16)(acc[mi][ni][r] + bvf);
      }
    }
  }
  __syncthreads();
  bf16* ob = out + (size_t)b * P * 256 + (size_t)p0 * 256;
#pragma unroll
  for (int pass = 0; pass < 8; ++pass) {
    int idx = pass * 256 + t;          // 2048 units of bf16x8
    int row = idx >> 5, cu = idx & 31;
    bf16x8 v = *(const bf16x8*)(Sc + row * 264 + cu * 8);
    *(bf16x8*)(ob + (size_t)row * 256 + cu * 8) = v;
  }
}

// ---------------------------------------------------------------------------
// In-place column softmax over x (per b,hd,y), x4 (R2 sum) folded in.
// ---------------------------------------------------------------------------
__global__ void smax_kernel(float* __restrict__ score) {
  __shared__ float s[6400];
  const int hd = blockIdx.x, b = blockIdx.y, t = threadIdx.x;
  float* buf = score + ((size_t)b * 4 + hd) * 6400;
  for (int i = t; i < 6400; i += 256) s[i] = buf[i];
  __syncthreads();
  if (t < 80) {
    const int y = t;
    float m = -1e30f;
    for (int x = 0; x < 80; ++x) m = fmaxf(m, s[x * 80 + y]);
    float sum = 0.f;
    for (int x = 0; x < 80; ++x) {
      float e = __expf(s[x * 80 + y] - m);
      s[x * 80 + y] = e;
      sum += e;
    }
    float inv = 4.0f / sum;
    for (int x = 0; x < 80; ++x) buf[x * 80 + y] = s[x * 80 + y] * inv;
  }
}

// ===========================================================================
// Uv[b][hd][o][q] = sum_{c<64} wo[o][hd*64+c] * V[b][q][hd*64+c]  (unchanged)
// ===========================================================================
__global__ __launch_bounds__(256, 4)
void uv_gemm(const bf16* __restrict__ Vpm, const bf16* __restrict__ Wo,
             bf16* __restrict__ Uv) {
  __shared__ alignas(16) bf16 Vt[64 * 64];
  const int t = threadIdx.x;
  const int b = blockIdx.z;
  const int hd = blockIdx.y;
  const int q0 = blockIdx.x * 64;
  const int w = t >> 6, l = t & 63;
  const int lrow = l & 15, ksel = l >> 4;

  const bf16* vsrc = Vpm + ((size_t)b * 1600 + q0) * 256 + hd * 64;
#pragma unroll
  for (int call = 0; call < 2; ++call) {
    int idx = (w * 2 + call) * 64 + l;
    int q = idx >> 3, u = idx & 7;
    gl16(vsrc + (size_t)q * 256 + ((u ^ (q & 7)) << 3), Vt + idx * 8);
  }
  asm volatile("s_waitcnt vmcnt(0)" ::: "memory");
  __syncthreads();

  f32x4 acc[4][4];
#pragma unroll
  for (int i = 0; i < 4; ++i)
#pragma unroll
    for (int j = 0; j < 4; ++j) acc[i][j] = (f32x4){0.f, 0.f, 0.f, 0.f};

#pragma unroll
  for (int kk = 0; kk < 2; ++kk) {
    bf16x8 af[4], bv[4];
#pragma unroll
    for (int mi = 0; mi < 4; ++mi)
      af[mi] = *(const bf16x8*)(Wo + (size_t)(w * 64 + mi * 16 + lrow) * 256 +
                                hd * 64 + kk * 32 + ksel * 8);
#pragma unroll
    for (int ni = 0; ni < 4; ++ni)
      bv[ni] = frag(Vt, ni * 16 + lrow, kk * 32 + ksel * 8);
#pragma unroll
    for (int mi = 0; mi < 4; ++mi)
#pragma unroll
      for (int ni = 0; ni < 4; ++ni)
        acc[mi][ni] = __builtin_amdgcn_mfma_f32_16x16x32_bf16(af[mi], bv[ni], acc[mi][ni], 0, 0, 0);
  }

  bf16* ob = Uv + ((size_t)(b * 4 + hd)) * 256 * 1600;
#pragma unroll
  for (int mi = 0; mi < 4; ++mi) {
#pragma unroll
    for (int ni = 0; ni < 4; ++ni) {
#pragma unroll
      for (int r = 0; r < 4; ++r) {
        int o = w * 64 + mi * 16 + ksel * 4 + r;
        int q = q0 + ni * 16 + lrow;
        ob[(size_t)o * 1600 + q] = (bf16)acc[mi][ni][r];
      }
    }
  }
}

// ===========================================================================
// combine (unchanged): one block per (o, b), coalesced writes.
// ===========================================================================
__global__ __launch_bounds__(256, 8)
void combine(const bf16* __restrict__ Uv, const float* __restrict__ attn,
             const float* __restrict__ bo, float* __restrict__ out) {
  __shared__ bf16 Us[4][1600];
  __shared__ int   sx0[80], sx1[80];
  __shared__ float swx[80];
  const int t = threadIdx.x;
  const int o = blockIdx.x;
  const int b = blockIdx.y;

  const bf16* usrc = Uv + (size_t)(b * 4) * 256 * 1600 + (size_t)o * 1600;
  for (int idx = t; idx < 800; idx += 256) {
    int hd = idx / 200, u = idx % 200;
    *(bf16x8*)&Us[hd][u * 8] = *(const bf16x8*)(usrc + (size_t)hd * 256 * 1600 + u * 8);
  }
  if (t < 80) {
    float c = 0.5f * t - 0.25f;
    int i0 = (int)floorf(c);
    swx[t] = c - i0;
    sx0[t] = i0 < 0 ? 0 : i0;
    sx1[t] = (i0 + 1 > 39) ? 39 : i0 + 1;
  }
  __syncthreads();

  const float bias = bo[o];
  const float* attb = attn + (size_t)b * 4 * 6400;
  float* op = out + ((size_t)b * 256 + o) * 6400;

  for (int p = t; p < 6400; p += 256) {
    int x = p / 80, y = p - x * 80;
    int x0 = sx0[x], x1 = sx1[x], y0 = sx0[y], y1 = sx1[y];
    float wx1 = swx[x], wy1 = swx[y];
    float w00 = (1.f - wx1) * (1.f - wy1), w01 = (1.f - wx1) * wy1;
    float w10 = wx1 * (1.f - wy1), w11 = wx1 * wy1;
    int q00 = x0 * 40 + y0, q01 = x0 * 40 + y1, q10 = x1 * 40 + y0, q11 = x1 * 40 + y1;
    float acc = bias;
#pragma unroll
    for (int hd = 0; hd < 4; ++hd) {
      float up = w00 * (float)Us[hd][q00] + w01 * (float)Us[hd][q01] +
                 w10 * (float)Us[hd][q10] + w11 * (float)Us[hd][q11];
      acc += attb[hd * 6400 + p] * up;
    }
    op[p] = acc;
  }
}

// ---------------------------------------------------------------------------
extern "C" void kernel_launch(void* const* d_in, const int* in_sizes, int n_in,
                              void* d_out, int out_size, void* d_ws, size_t ws_size,
                              hipStream_t stream) {
  const float* query = (const float*)d_in[0];
  const float* key   = (const float*)d_in[1];
  const float* wq    = (const float*)d_in[2];
  const float* bq    = (const float*)d_in[3];
  const float* wk    = (const float*)d_in[4];
  const float* bk    = (const float*)d_in[5];
  const float* wv    = (const float*)d_in[6];
  const float* bv    = (const float*)d_in[7];
  const float* wo    = (const float*)d_in[8];
  const float* bo    = (const float*)d_in[9];

  // ws layout (85.7 MB): Uv | Kpm | Vpm | score(+attn in-place) | Wb
  char* ws = (char*)d_ws;
  bf16*  Uv    = (bf16*)(ws);              // 52,428,800 B  [b][hd][o][q]
  bf16*  Kpm   = (bf16*)(ws + 52428800);   // 13,107,200 B
  bf16*  Vpm   = (bf16*)(ws + 65536000);   // 13,107,200 B
  float* score = (float*)(ws + 78643200);  //  6,553,600 B
  bf16*  Wb    = (bf16*)(ws + 85196800);   //    524,288 B
  bf16* wqb = Wb, *wkb = Wb + 65536, *wvb = Wb + 131072, *wob = Wb + 196608;

  wpre<<<dim3(32, 4), 256, 0, stream>>>(wq, wk, wv, wo, Wb);
  kv_proj<<<dim3(25, 2, 16), 256, 0, stream>>>(key, wkb, bk, Kpm, wvb, bv, Vpm);
  qscore<<<dim3(100, 1, 16), 256, 0, stream>>>(query, wqb, bq, Kpm, score);
  smax_kernel<<<dim3(4, 16), 256, 0, stream>>>(score);
  uv_gemm<<<dim3(25, 4, 16), 256, 0, stream>>>(Vpm, wob, Uv);
  combine<<<dim3(256, 16), 256, 0, stream>>>(Uv, score, bo, (float*)d_out);
}